// Round 25
// baseline (919.769 us; speedup 1.0000x reference)
//
#include <hip/hip_runtime.h>

typedef unsigned int uint32;
typedef unsigned long long uint64;
typedef __attribute__((ext_vector_type(4))) float  f32x4;
typedef __attribute__((ext_vector_type(8))) short  bf16x8;
typedef __attribute__((ext_vector_type(4))) unsigned short us4;
typedef __attribute__((ext_vector_type(8))) unsigned short us8;

#define N_ROWS   16384
#define D_IN     512
#define D_DICT   8192
#define TOPK     256
#define BAND     1.5e-2f
#define BCAP     64
#define CCAP     2048
#define CAND_CAP 1024
#define TFIX     1.38f
#define BINW     0.01f     // r19-r24-validated bin width

__device__ __forceinline__ unsigned short f2bf_rne(float f) {
    unsigned u = __float_as_uint(f);
    unsigned r = u + 0x7FFFu + ((u >> 16) & 1u);
    return (unsigned short)(r >> 16);
}
__device__ __forceinline__ float bf2f(unsigned short h) {
    return __uint_as_float(((unsigned)h) << 16);
}
__device__ __forceinline__ uint32 okey(float v) {
    uint32 u = __float_as_uint(v);
    return (u & 0x80000000u) ? ~u : (u | 0x80000000u);
}
__device__ __forceinline__ float inv_okey(uint32 u) {
    uint32 bits = (u & 0x80000000u) ? (u & 0x7FFFFFFFu) : ~u;
    return __uint_as_float(bits);
}
// XOR-swizzled LDS element address (validated r5-r24)
__device__ __forceinline__ int swz(int row, int k) {
    return row * 64 + (k ^ ((row & 7) << 3));
}
__device__ __forceinline__ void gll16(const unsigned short* g, unsigned short* l) {
    __builtin_amdgcn_global_load_lds(
        (const __attribute__((address_space(1))) unsigned int*)g,
        (__attribute__((address_space(3))) unsigned int*)l, 16, 0, 0);
}

// ---------------------------------------------------------------------------
// Kernel 0: fp32 -> bf16 cast with per-row LDS XOR swizzle baked in.
// ---------------------------------------------------------------------------
__launch_bounds__(256)
__global__ void cast_swz_kernel(const float* __restrict__ src,
                                unsigned short* __restrict__ dst,
                                int gprl) {
    int idx = blockIdx.x * 256 + threadIdx.x;
    int row = idx >> gprl;
    int g   = idx & ((1 << gprl) - 1);
    const float* s = src + ((size_t)idx << 3);
    us8 o;
    #pragma unroll
    for (int j = 0; j < 8; ++j) o[j] = f2bf_rne(s[j]);
    int gout = (g & ~7) | ((g ^ row) & 7);
    *(us8*)&dst[(((size_t)row << gprl) + gout) << 3] = o;
}

// ---------------------------------------------------------------------------
// Kernel 1 (v6): single-term bf16 MFMA encode + ballot candidate push
// (validated r22/r24: 3 blocks/CU, ballot epilogue).
// ---------------------------------------------------------------------------
__launch_bounds__(256, 3)
__global__ void encode_mfma_cand(const unsigned short* __restrict__ Xb,
                                 const unsigned short* __restrict__ Web,
                                 const float* __restrict__ b_enc,
                                 uint2* __restrict__ Cand,
                                 uint32* __restrict__ CandCnt) {
    __shared__ unsigned short At[128 * 64];
    __shared__ unsigned short Bt[128 * 64];

    int tid  = threadIdx.x;
    int lane = tid & 63;
    int wid  = tid >> 6;
    int wm   = wid >> 1;
    int wn   = wid & 1;
    int bn   = blockIdx.x * 128;
    int bm   = blockIdx.y * 128;
    int fr   = lane & 15;

    f32x4 acc[4][4];
    #pragma unroll
    for (int i = 0; i < 4; ++i)
        #pragma unroll
        for (int j = 0; j < 4; ++j) acc[i][j] = (f32x4)0.f;

    for (int c = 0; c < 8; ++c) {
        #pragma unroll
        for (int q = 0; q < 4; ++q) {
            int s = q * 256 + tid;
            int row = s >> 3;
            int g8  = (s & 7) * 8;
            gll16(&Xb[(size_t)(bm + row) * D_IN + c * 64 + g8], &At[row * 64 + g8]);
            gll16(&Web[(size_t)(bn + row) * D_IN + c * 64 + g8], &Bt[row * 64 + g8]);
        }
        __syncthreads();

        #pragma unroll
        for (int ks = 0; ks < 2; ++ks) {
            int kb = ks * 32 + (lane >> 4) * 8;
            bf16x8 av[4], bv[4];
            #pragma unroll
            for (int nj = 0; nj < 4; ++nj)
                bv[nj] = *(const bf16x8*)&Bt[swz(wn * 64 + nj * 16 + fr, kb)];
            #pragma unroll
            for (int mi = 0; mi < 4; ++mi)
                av[mi] = *(const bf16x8*)&At[swz(wm * 64 + mi * 16 + fr, kb)];
            #pragma unroll
            for (int mi = 0; mi < 4; ++mi)
                #pragma unroll
                for (int nj = 0; nj < 4; ++nj)
                    acc[mi][nj] = __builtin_amdgcn_mfma_f32_16x16x32_bf16(
                        av[mi], bv[nj], acc[mi][nj], 0, 0, 0);
        }
        __syncthreads();
    }

    float bcol[4];
    #pragma unroll
    for (int nj = 0; nj < 4; ++nj)
        bcol[nj] = b_enc[bn + wn * 64 + nj * 16 + fr];

    uint64 lowmask = (1ull << lane) - 1ull;
    uint64 grpmask = 0xFFFFull << (lane & 48);

    #pragma unroll
    for (int mi = 0; mi < 4; ++mi) {
        int rbase = bm + wm * 64 + mi * 16 + (lane >> 4) * 4;
        #pragma unroll
        for (int reg = 0; reg < 4; ++reg) {
            int r = rbase + reg;
            float v[4];
            uint64 m[4];
            #pragma unroll
            for (int nj = 0; nj < 4; ++nj) {
                v[nj] = acc[mi][nj][reg] + bcol[nj];
                m[nj] = __ballot(v[nj] > TFIX);
            }
            int c0 = __popcll(m[0] & grpmask);
            int c1 = __popcll(m[1] & grpmask);
            int c2 = __popcll(m[2] & grpmask);
            int c3 = __popcll(m[3] & grpmask);
            int total = c0 + c1 + c2 + c3;
            if (total > 0) {
                int base = 0;
                if (fr == 0) base = (int)atomicAdd(&CandCnt[r], (uint32)total);
                base = __shfl(base, lane & 48);
                int pre[4] = {0, c0, c0 + c1, c0 + c1 + c2};
                #pragma unroll
                for (int nj = 0; nj < 4; ++nj) {
                    if (v[nj] > TFIX) {
                        int slot = base + pre[nj] +
                                   __popcll(m[nj] & grpmask & lowmask);
                        if (slot < CAND_CAP)
                            Cand[(size_t)r * CAND_CAP + slot] =
                                make_uint2(__float_as_uint(v[nj]),
                                           (uint32)(bn + wn * 64 + nj * 16 + fr));
                    }
                }
            }
        }
    }
}

// ---------------------------------------------------------------------------
// Kernel 2: select — pairs only (validated r19-r24).
// ---------------------------------------------------------------------------
__launch_bounds__(256)
__global__ void select_kernel(const uint2* __restrict__ Cand,
                              const uint32* __restrict__ CandCnt,
                              const float* __restrict__ x,
                              const float* __restrict__ Wenc,
                              const float* __restrict__ b_enc,
                              uint32* __restrict__ Pairs,   // [N_ROWS][256]
                              uint32* __restrict__ flags) {
    __shared__ float  cand_val[CAND_CAP];
    __shared__ int    cand_idx[CAND_CAP];
    __shared__ uint32 hist[256];
    __shared__ uint32 pk[256];
    __shared__ uint64 bkey[BCAP];
    __shared__ int    sh_bin;
    __shared__ int    c_clear, bcnt;
    __shared__ int    bidx_s[BCAP];
    __shared__ float  bval_s[BCAP];

    int row = blockIdx.x;
    int t = threadIdx.x;

    int n = (int)CandCnt[row];
    bool ok = (n >= TOPK && n <= CAND_CAP);

    hist[t] = 0;
    if (t == 0) { sh_bin = 255; c_clear = 0; bcnt = 0; }
    if (ok) {
        for (int e = t; e < n; e += 256) {
            uint2 cv = Cand[(size_t)row * CAND_CAP + e];
            cand_val[e] = __uint_as_float(cv.x);
            cand_idx[e] = (int)cv.y;
        }
    }
    __syncthreads();

    float vL = 0.f, vU = 0.f;
    if (ok) {
        for (int e = t; e < n; e += 256) {
            int b = (int)((cand_val[e] - TFIX) * (1.f / BINW));
            b = b < 0 ? 0 : (b > 255 ? 255 : b);
            atomicAdd(&hist[b], 1u);
        }
        __syncthreads();
        if (t < 64) {
            uint4 h4 = *(const uint4*)&hist[t * 4];
            uint32 lsum = h4.x + h4.y + h4.z + h4.w;
            uint32 s = lsum;
            #pragma unroll
            for (int off = 1; off < 64; off <<= 1) {
                uint32 vv = __shfl_down(s, off);
                if (t + off < 64) s += vv;
            }
            uint32 above = s - lsum;
            uint32 suf3 = above + h4.w;
            uint32 suf2 = suf3 + h4.z;
            uint32 suf1 = suf2 + h4.y;
            uint32 suf0 = suf1 + h4.x;
            uint32 need = TOPK;
            if (above < need && suf0 >= need) {
                int j;
                if (suf3 >= need)      j = 3;
                else if (suf2 >= need) j = 2;
                else if (suf1 >= need) j = 1;
                else                   j = 0;
                sh_bin = t * 4 + j;
            }
        }
        __syncthreads();
        int b = sh_bin;
        vL = TFIX + BINW * b - 1e-3f;
        vU = TFIX + BINW * (b + 1) + 1e-3f;
        if (b >= 255) ok = false;
        if (!(vL - BAND - 1e-3f > TFIX)) ok = false;
    }

    if (!ok) {
        if (t == 0) flags[row] = 1u;
        return;
    }

    for (int e = t; e < n; e += 256) {
        float v = cand_val[e];
        int i = cand_idx[e];
        if (v > vU + BAND) {
            atomicAdd((uint32*)&c_clear, 1u);
        } else if (v >= vL - BAND) {
            int slot = atomicAdd((uint32*)&bcnt, 1u);
            if (slot < BCAP) bidx_s[slot] = i;
        }
    }
    __syncthreads();

    if (bcnt > BCAP) {
        if (t == 0) flags[row] = 1u;
        return;
    }

    if (t == 0) c_clear = 0;
    __syncthreads();
    for (int e = t; e < n; e += 256) {
        float v = cand_val[e];
        int i = cand_idx[e];
        if (v > vU + BAND) {
            int slot = atomicAdd((uint32*)&c_clear, 1u);
            pk[slot] = ((uint32)f2bf_rne(v) << 16) | (uint32)i;
        }
    }

    int nb = bcnt;
    if (t < nb) {
        const float* xr = x + (size_t)row * D_IN;
        const float* wr = Wenc + (size_t)bidx_s[t] * D_IN;
        float acc = 0.f;
        #pragma unroll 8
        for (int k = 0; k < D_IN; ++k)   // ascending k — np rounding class
            acc = fmaf(xr[k], wr[k], acc);
        bval_s[t] = acc + b_enc[bidx_s[t]];
    }
    if (t < BCAP)
        bkey[t] = 0xFFFFFFFFFFFFFFFFull;
    __syncthreads();
    if (t < nb)
        bkey[t] = ((uint64)(~okey(bval_s[t])) << 32) | (uint32)bidx_s[t];
    __syncthreads();
    for (int k = 2; k <= BCAP; k <<= 1) {
        for (int j = k >> 1; j > 0; j >>= 1) {
            if (t < BCAP) {
                int l = t ^ j;
                if (l > t) {
                    uint64 a = bkey[t], b = bkey[l];
                    bool up = ((t & k) == 0);
                    if ((a > b) == up) { bkey[t] = b; bkey[l] = a; }
                }
            }
            __syncthreads();
        }
    }
    int take = TOPK - c_clear;
    if (t < take) {
        uint64 key = bkey[t];
        uint32 ok32 = ~(uint32)(key >> 32);
        int    idx  = (int)(uint32)(key & 0xFFFFFFFFull);
        float  hv   = fmaxf(inv_okey(ok32), 0.f);
        pk[c_clear + t] = ((uint32)f2bf_rne(hv) << 16) | (uint32)idx;
    }
    __syncthreads();

    for (int k = 2; k <= 256; k <<= 1) {
        for (int j = k >> 1; j > 0; j >>= 1) {
            int l = t ^ j;
            if (l > t) {
                uint32 a = pk[t], b = pk[l];
                bool up = ((t & k) == 0);
                if (((a & 0xFFFFu) > (b & 0xFFFFu)) == up) { pk[t] = b; pk[l] = a; }
            }
            __syncthreads();
        }
    }
    Pairs[(size_t)row * 256 + t] = pk[t];
}

// ---------------------------------------------------------------------------
// Kernel 2b: exact repair for flagged rows — emits sorted Pairs (validated r18-r24).
// ---------------------------------------------------------------------------
__launch_bounds__(256)
__global__ void repair_kernel(const uint32* __restrict__ flags,
                              const float* __restrict__ x,
                              const float* __restrict__ Wenc,
                              const float* __restrict__ b_enc,
                              uint32* __restrict__ Pairs) {
    int row = blockIdx.x;
    if (flags[row] == 0u) return;
    __shared__ float  vals[D_DICT];
    __shared__ float  xs[D_IN];
    __shared__ uint32 hist[256];
    __shared__ uint32 pscan[257];
    __shared__ uint32 cnt_eq[256];
    __shared__ int    offs[257];
    __shared__ uint32 sh_prefix, sh_need;
    int t = threadIdx.x;

    for (int c = t; c < D_IN; c += 256) xs[c] = x[(size_t)row * D_IN + c];
    __syncthreads();
    for (int e = t; e < D_DICT; e += 256) {
        const float* wr = Wenc + (size_t)e * D_IN;
        float acc = 0.f;
        #pragma unroll 8
        for (int k = 0; k < D_IN; ++k)   // ascending k — np rounding class
            acc = fmaf(xs[k], wr[k], acc);
        vals[e] = acc + b_enc[e];
    }
    __syncthreads();

    uint32 prefix = 0, need = TOPK;
    for (int pass = 0; pass < 4; ++pass) {
        int shift = 24 - 8 * pass;
        hist[t] = 0;
        __syncthreads();
        uint32 mask_hi = pass ? (0xFFFFFFFFu << (shift + 8)) : 0u;
        #pragma unroll 4
        for (int c = 0; c < 32; ++c) {
            uint32 u = okey(vals[c * 256 + t]);
            if ((u & mask_hi) == prefix)
                atomicAdd(&hist[(u >> shift) & 255u], 1u);
        }
        __syncthreads();
        if (t == 0) {
            uint32 cum = 0;
            int d = 255;
            for (; d > 0; --d) {
                uint32 h = hist[d];
                if (cum + h >= need) break;
                cum += h;
            }
            sh_prefix = prefix | ((uint32)d << shift);
            sh_need = need - cum;
        }
        __syncthreads();
        prefix = sh_prefix;
        need = sh_need;
        __syncthreads();
    }
    uint32 T = prefix;
    uint32 r = need;

    #pragma unroll 2
    for (int c = 0; c < 32; ++c) {
        int i = c * 256 + t;
        uint32 u = okey(vals[i]);
        vals[i] = (u > T) ? fmaxf(vals[i], 0.f) : 0.f;
    }
    __syncthreads();

    cnt_eq[t] = 0;
    __syncthreads();
    {
        const float* xr = xs;
        for (int e = t; e < D_DICT; e += 256) {
            const float* wr = Wenc + (size_t)e * D_IN;
            float acc = 0.f;
            #pragma unroll 8
            for (int k = 0; k < D_IN; ++k)
                acc = fmaf(xr[k], wr[k], acc);
            float ov = acc + b_enc[e];
            if (okey(ov) == T) atomicAdd(&cnt_eq[e >> 5], 1u);
        }
    }
    __syncthreads();
    if (t == 0) {
        uint32 s = 0;
        for (int i = 0; i < 256; ++i) { pscan[i] = s; s += cnt_eq[i]; }
    }
    __syncthreads();
    {
        uint32 segbase = pscan[t];
        const float* xr = xs;
        uint32 rank = segbase;
        for (int j = 0; j < 32 && rank < r; ++j) {
            int i = t * 32 + j;
            const float* wr = Wenc + (size_t)i * D_IN;
            float acc = 0.f;
            #pragma unroll 8
            for (int k = 0; k < D_IN; ++k)
                acc = fmaf(xr[k], wr[k], acc);
            float ov = acc + b_enc[i];
            if (okey(ov) == T) {
                vals[i] = fmaxf(ov, 0.f);
                rank++;
            }
        }
    }
    __syncthreads();

    int base2 = t * 32;
    int c2 = 0;
    for (int j = 0; j < 32; ++j) c2 += (vals[base2 + j] > 0.f) ? 1 : 0;
    offs[t + 1] = c2;
    __syncthreads();
    if (t == 0) {
        offs[0] = 0;
        for (int i = 0; i < 256; ++i) offs[i + 1] += offs[i];
    }
    __syncthreads();
    int o = offs[t];
    for (int j = 0; j < 32; ++j) {
        float v = vals[base2 + j];
        if (v > 0.f) {
            Pairs[(size_t)row * 256 + o] =
                ((uint32)f2bf_rne(v) << 16) | (uint32)(base2 + j);
            ++o;
        }
    }
    __syncthreads();
    int total = offs[256];
    for (int e = total + t; e < 256; e += 256)
        Pairs[(size_t)row * 256 + e] = 0x0000FFFFu;
}

// ---------------------------------------------------------------------------
// Kernel 3 (v6b): pairs decode, column-split 64x256 / 512 thr / grid 512
// (validated r21/r22/r24) + XCD-aligned col-half remap: q=bid&3, h=(bid>>2)&1,
// g=bid>>3 -> bm=(g*4+q)*64, ch=h. Under bid%8 round-robin dispatch, XCDs 0-3
// always serve ch=0 and XCDs 4-7 always ch=1 -> each XCD touches one 4MB Wb
// half (fits its L2). Bijective (row-block, ch) mapping -> output unchanged.
// ---------------------------------------------------------------------------
__launch_bounds__(512)
__global__ void mfma_decode_pairs(const uint32* __restrict__ Pairs,
                                  const unsigned short* __restrict__ Wb,
                                  const float* __restrict__ b_dec,
                                  float* __restrict__ recon,
                                  float* __restrict__ hidden) {
    __shared__ unsigned short At[2][64 * 64];   // 16KB double-buffered
    __shared__ unsigned short Bt[256 * 64];     // 32KB
    __shared__ int curs[64];

    int tid  = threadIdx.x;
    int lane = tid & 63;
    int wn   = tid >> 6;
    int bid  = blockIdx.x;
    int ch   = (bid >> 2) & 1;                 // XCD-aligned col half
    int bm   = ((bid >> 3) * 4 + (bid & 3)) * 64;
    int fr   = lane & 15;
    int dbase = ch * 256;

    int pr_r = tid >> 3;
    int pr_j = tid & 7;
    int sub8 = (lane >> 3) * 8;
    const uint32* prow = Pairs + (size_t)(bm + pr_r) * 256;

    if (tid < 64) curs[tid] = 0;
    *(us8*)&At[0][tid * 8] = (us8)0;
    *(us8*)&At[1][tid * 8] = (us8)0;
    __syncthreads();

    f32x4 acc[4][2];
    #pragma unroll
    for (int i = 0; i < 4; ++i)
        #pragma unroll
        for (int j = 0; j < 2; ++j) acc[i][j] = (f32x4)0.f;

    for (int k0 = 0; k0 < D_DICT; k0 += 64) {
        int cur = (k0 >> 6) & 1;
        unsigned short* Ac = At[cur];

        #pragma unroll
        for (int q = 0; q < 4; ++q) {
            int s = q * 512 + tid;
            int row = s >> 3;
            int b8  = (s & 7) * 8;
            gll16(&Wb[(size_t)(dbase + row) * D_DICT + k0 + b8], &Bt[row * 64 + b8]);
        }
        {
            int kend = k0 + 64;
            int cur2 = curs[pr_r];
            for (;;) {
                int e = cur2 + pr_j;
                uint32 p = (e < 256) ? prow[e] : 0x0000FFFFu;
                int idx = (int)(p & 0xFFFFu);
                bool in = (idx < kend);
                if (in)
                    Ac[pr_r * 64 + ((idx - k0) ^ ((pr_r & 7) << 3))] =
                        (unsigned short)(p >> 16);
                uint64 mask = __ballot(in);
                int cnt = __popcll((mask >> sub8) & 0xFFull);
                cur2 += cnt;
                if (cnt < 8) break;
            }
            if (pr_j == 0) curs[pr_r] = cur2;
        }
        __syncthreads();

        if (ch == 0) {
            int row = tid >> 3;
            int g   = tid & 7;
            us8 w = *(const us8*)&Ac[row * 64 + g * 8];
            int lg = g ^ (row & 7);
            float* hdst = &hidden[(size_t)(bm + row) * D_DICT + k0 + lg * 8];
            float4 o0, o1;
            o0.x = bf2f(w[0]); o0.y = bf2f(w[1]);
            o0.z = bf2f(w[2]); o0.w = bf2f(w[3]);
            o1.x = bf2f(w[4]); o1.y = bf2f(w[5]);
            o1.z = bf2f(w[6]); o1.w = bf2f(w[7]);
            *(float4*)&hdst[0] = o0;
            *(float4*)&hdst[4] = o1;
        }

        #pragma unroll
        for (int ks = 0; ks < 2; ++ks) {
            int kb = ks * 32 + (lane >> 4) * 8;
            bf16x8 av[4], bv[2];
            #pragma unroll
            for (int mi = 0; mi < 4; ++mi)
                av[mi] = *(const bf16x8*)&Ac[swz(mi * 16 + fr, kb)];
            #pragma unroll
            for (int nj = 0; nj < 2; ++nj)
                bv[nj] = *(const bf16x8*)&Bt[swz(wn * 32 + nj * 16 + fr, kb)];
            #pragma unroll
            for (int mi = 0; mi < 4; ++mi)
                #pragma unroll
                for (int nj = 0; nj < 2; ++nj)
                    acc[mi][nj] = __builtin_amdgcn_mfma_f32_16x16x32_bf16(
                        av[mi], bv[nj], acc[mi][nj], 0, 0, 0);
        }

        *(us8*)&At[cur ^ 1][tid * 8] = (us8)0;
        __syncthreads();
    }

    #pragma unroll
    for (int mi = 0; mi < 4; ++mi) {
        int r0 = bm + mi * 16 + (lane >> 4) * 4;
        #pragma unroll
        for (int nj = 0; nj < 2; ++nj) {
            int col = dbase + wn * 32 + nj * 16 + fr;
            float bd = b_dec[col];
            #pragma unroll
            for (int reg = 0; reg < 4; ++reg)
                recon[(size_t)(r0 + reg) * D_IN + col] = acc[mi][nj][reg] + bd;
        }
    }
}

// ---------------------------------------------------------------------------
// Tier C fallback kernels (validated r10-r24)
// ---------------------------------------------------------------------------
#define EBK 8
#define ESTR 132

__launch_bounds__(256)
__global__ void encode_gemm_kernel(const float* __restrict__ X,
                                   const float* __restrict__ Wenc,
                                   const float* __restrict__ b_enc,
                                   float* __restrict__ P,
                                   int row0, int nrows) {
    __shared__ float As[EBK][ESTR];
    __shared__ float Bs[EBK][ESTR];
    int tid = threadIdx.x;
    int tx = tid & 15;
    int ty = tid >> 4;
    int bm = blockIdx.x * 128;
    int bn = blockIdx.y * 128;
    int srow = tid >> 1;
    int skq  = (tid & 1) * 4;

    float acc[8][8];
    #pragma unroll
    for (int i = 0; i < 8; ++i)
        #pragma unroll
        for (int j = 0; j < 8; ++j) acc[i][j] = 0.f;

    for (int k0 = 0; k0 < D_IN; k0 += EBK) {
        float4 a4 = make_float4(0.f, 0.f, 0.f, 0.f);
        if (bm + srow < nrows)
            a4 = *(const float4*)&X[(size_t)(row0 + bm + srow) * D_IN + k0 + skq];
        float4 b4 = *(const float4*)&Wenc[(size_t)(bn + srow) * D_IN + k0 + skq];
        As[skq + 0][srow] = a4.x; As[skq + 1][srow] = a4.y;
        As[skq + 2][srow] = a4.z; As[skq + 3][srow] = a4.w;
        Bs[skq + 0][srow] = b4.x; Bs[skq + 1][srow] = b4.y;
        Bs[skq + 2][srow] = b4.z; Bs[skq + 3][srow] = b4.w;
        __syncthreads();
        #pragma unroll
        for (int k = 0; k < EBK; ++k) {
            float4 a0 = *(const float4*)&As[k][ty * 4];
            float4 a1 = *(const float4*)&As[k][64 + ty * 4];
            float4 b0 = *(const float4*)&Bs[k][tx * 4];
            float4 b1 = *(const float4*)&Bs[k][64 + tx * 4];
            float a[8] = {a0.x, a0.y, a0.z, a0.w, a1.x, a1.y, a1.z, a1.w};
            float b[8] = {b0.x, b0.y, b0.z, b0.w, b1.x, b1.y, b1.z, b1.w};
            #pragma unroll
            for (int i = 0; i < 8; ++i)
                #pragma unroll
                for (int j = 0; j < 8; ++j)
                    acc[i][j] = fmaf(a[i], b[j], acc[i][j]);
        }
        __syncthreads();
    }

    float4 bias0 = *(const float4*)&b_enc[bn + tx * 4];
    float4 bias1 = *(const float4*)&b_enc[bn + 64 + tx * 4];
    float bb[8] = {bias0.x, bias0.y, bias0.z, bias0.w,
                   bias1.x, bias1.y, bias1.z, bias1.w};
    #pragma unroll
    for (int i = 0; i < 8; ++i) {
        int r = bm + (i < 4 ? ty * 4 + i : 64 + ty * 4 + (i - 4));
        if (r < nrows) {
            float4 o0, o1;
            o0.x = acc[i][0] + bb[0]; o0.y = acc[i][1] + bb[1];
            o0.z = acc[i][2] + bb[2]; o0.w = acc[i][3] + bb[3];
            o1.x = acc[i][4] + bb[4]; o1.y = acc[i][5] + bb[5];
            o1.z = acc[i][6] + bb[6]; o1.w = acc[i][7] + bb[7];
            *(float4*)&P[(size_t)r * D_DICT + bn + tx * 4] = o0;
            *(float4*)&P[(size_t)r * D_DICT + bn + 64 + tx * 4] = o1;
        }
    }
}

__launch_bounds__(256)
__global__ void topk_band_kernel(const float* __restrict__ P,
                                 int row0,
                                 const float* __restrict__ x,
                                 const float* __restrict__ Wenc,
                                 const float* __restrict__ b_enc,
                                 float* __restrict__ hidden) {
    __shared__ float  cand_val[CCAP];
    __shared__ int    cand_idx[CCAP];
    __shared__ uint32 hist[256];
    __shared__ float  redS[4], redS2[4];
    __shared__ float  sh_mu, sh_sig;
    __shared__ uint32 sh_prefix, sh_need;
    __shared__ int    sh_cnt, c_clear, bcnt;
    __shared__ int    bidx_s[BCAP];
    __shared__ float  bval_s[BCAP];

    int lrow = blockIdx.x;
    int grow = row0 + lrow;
    const float* p = P + (size_t)lrow * D_DICT;
    float* hrow = hidden + (size_t)grow * D_DICT;
    int t = threadIdx.x;

    if (t == 0) sh_cnt = 0;
    float s = 0.f, s2 = 0.f;
    #pragma unroll 2
    for (int c = 0; c < 8; ++c) {
        int e4 = c * 256 + t;
        float4 v4 = ((const float4*)p)[e4];
        s  += v4.x + v4.y + v4.z + v4.w;
        s2 += v4.x*v4.x + v4.y*v4.y + v4.z*v4.z + v4.w*v4.w;
        *(float4*)&hrow[e4 * 4] = make_float4(0.f, 0.f, 0.f, 0.f);
    }
    #pragma unroll
    for (int off = 32; off; off >>= 1) {
        s  += __shfl_down(s, off);
        s2 += __shfl_down(s2, off);
    }
    if ((t & 63) == 0) { redS[t >> 6] = s; redS2[t >> 6] = s2; }
    __syncthreads();
    if (t == 0) {
        float S  = redS[0] + redS[1] + redS[2] + redS[3];
        float S2 = redS2[0] + redS2[1] + redS2[2] + redS2[3];
        float mu = S * (1.f / D_DICT);
        float var = S2 * (1.f / D_DICT) - mu * mu;
        sh_mu = mu;
        sh_sig = sqrtf(fmaxf(var, 1e-20f));
    }
    __syncthreads();
    float Tlo = sh_mu + 1.3f * sh_sig;

    #pragma unroll 2
    for (int c = 0; c < 8; ++c) {
        int e4 = c * 256 + t;
        float4 v4 = ((const float4*)p)[e4];
        float vv[4] = {v4.x, v4.y, v4.z, v4.w};
        #pragma unroll
        for (int j = 0; j < 4; ++j) {
            if (vv[j] > Tlo) {
                int slot = atomicAdd((uint32*)&sh_cnt, 1u);
                if (slot < CCAP) { cand_val[slot] = vv[j]; cand_idx[slot] = e4 * 4 + j; }
            }
        }
    }
    __syncthreads();
    int n = sh_cnt;
    bool found = (n >= TOPK && n <= CCAP);

    float vT0 = 0.f;
    for (int rtry = 0; rtry < 2; ++rtry) {
        uint32 prefix = 0, need = TOPK;
        for (int pass = 0; pass < 4; ++pass) {
            int shift = 24 - 8 * pass;
            hist[t] = 0;
            __syncthreads();
            uint32 mask_hi = pass ? (0xFFFFFFFFu << (shift + 8)) : 0u;
            if (found) {
                for (int e = t; e < n; e += 256) {
                    uint32 u = okey(cand_val[e]);
                    if ((u & mask_hi) == prefix)
                        atomicAdd(&hist[(u >> shift) & 255u], 1u);
                }
            } else {
                for (int e = t; e < D_DICT; e += 256) {
                    uint32 u = okey(p[e]);
                    if ((u & mask_hi) == prefix)
                        atomicAdd(&hist[(u >> shift) & 255u], 1u);
                }
            }
            __syncthreads();
            if (t == 0) {
                uint32 cum = 0;
                int d = 255;
                for (; d > 0; --d) {
                    uint32 h = hist[d];
                    if (cum + h >= need) break;
                    cum += h;
                }
                sh_prefix = prefix | ((uint32)d << shift);
                sh_need = need - cum;
            }
            __syncthreads();
            prefix = sh_prefix;
            need = sh_need;
            __syncthreads();
        }
        uint32 tb = (prefix & 0x80000000u) ? (prefix & 0x7FFFFFFFu) : ~prefix;
        vT0 = __uint_as_float(tb);
        if (!found) break;
        if (vT0 - BAND - 1e-3f > Tlo) break;
        found = false;
        __syncthreads();
    }

    if (t == 0) { c_clear = 0; bcnt = 0; }
    __syncthreads();
    if (found) {
        for (int e = t; e < n; e += 256) {
            float v = cand_val[e];
            int i = cand_idx[e];
            if (v > vT0 + BAND) {
                hrow[i] = fmaxf(v, 0.f);
                atomicAdd((uint32*)&c_clear, 1u);
            } else if (v >= vT0 - BAND) {
                int slot = atomicAdd((uint32*)&bcnt, 1u);
                if (slot < BCAP) bidx_s[slot] = i;
            }
        }
    } else {
        for (int e = t; e < D_DICT; e += 256) {
            float v = p[e];
            if (v > vT0 + BAND) {
                hrow[e] = fmaxf(v, 0.f);
                atomicAdd((uint32*)&c_clear, 1u);
            } else if (v >= vT0 - BAND) {
                int slot = atomicAdd((uint32*)&bcnt, 1u);
                if (slot < BCAP) bidx_s[slot] = e;
            }
        }
    }
    __syncthreads();

    int nb = bcnt < BCAP ? bcnt : BCAP;
    if (t < nb) {
        const float* xr = x + (size_t)grow * D_IN;
        const float* wr = Wenc + (size_t)bidx_s[t] * D_IN;
        float acc = 0.f;
        #pragma unroll 8
        for (int k = 0; k < D_IN; ++k)
            acc = fmaf(xr[k], wr[k], acc);
        bval_s[t] = acc + b_enc[bidx_s[t]];
    }
    __syncthreads();
    if (t == 0) {
        int take = TOPK - c_clear;
        for (int rr = 0; rr < take; ++rr) {
            int best = -1; float bv = 0.f; int bi = 0;
            for (int e = 0; e < nb; ++e) {
                int idx = bidx_s[e];
                if (idx < 0) continue;
                float v = bval_s[e];
                if (best < 0 || v > bv || (v == bv && idx < bi)) {
                    best = e; bv = v; bi = idx;
                }
            }
            if (best < 0) break;
            bidx_s[best] = -1;
            hrow[bi] = fmaxf(bv, 0.f);
        }
    }
}

__launch_bounds__(256)
__global__ void decode_direct_kernel(const float* __restrict__ hidden,
                                     const float* __restrict__ W_dec,
                                     const float* __restrict__ b_dec,
                                     float* __restrict__ recon) {
    __shared__ float  sv[TOPK];
    __shared__ int    sidx[TOPK];
    __shared__ int    offs[257];
    int row = blockIdx.x;
    int t = threadIdx.x;
    const float* hrow = hidden + (size_t)row * D_DICT;

    int base = t * 32;
    int c = 0;
    for (int j = 0; j < 32; ++j) c += (hrow[base + j] > 0.f) ? 1 : 0;
    offs[t + 1] = c;
    __syncthreads();
    if (t == 0) {
        offs[0] = 0;
        for (int i = 0; i < 256; ++i) offs[i + 1] += offs[i];
    }
    __syncthreads();
    int o = offs[t];
    for (int j = 0; j < 32; ++j) {
        float v = hrow[base + j];
        if (v > 0.f) { sv[o] = v; sidx[o] = base + j; ++o; }
    }
    __syncthreads();
    int total = offs[256];

    int d0 = 2 * t;
    float acc0 = b_dec[d0];
    float acc1 = b_dec[d0 + 1];
    for (int k = 0; k < total; ++k) {
        float v = sv[k];
        int idx = sidx[k];
        acc0 = fmaf(v, W_dec[(size_t)d0 * D_DICT + idx], acc0);
        acc1 = fmaf(v, W_dec[(size_t)(d0 + 1) * D_DICT + idx], acc1);
    }
    *(float2*)&recon[(size_t)row * D_IN + d0] = make_float2(acc0, acc1);
}

// ---------------------------------------------------------------------------
extern "C" void kernel_launch(void* const* d_in, const int* in_sizes, int n_in,
                              void* d_out, int out_size, void* d_ws, size_t ws_size,
                              hipStream_t stream) {
    const float* x     = (const float*)d_in[0];
    const float* W_enc = (const float*)d_in[1];
    const float* b_enc = (const float*)d_in[2];
    const float* W_dec = (const float*)d_in[3];
    const float* b_dec = (const float*)d_in[4];

    float* out    = (float*)d_out;
    float* recon  = out;                          // 16384*512 fp32
    float* hidden = out + (size_t)N_ROWS * D_IN;  // 16384*8192 fp32

    const size_t CNT_BYTES   = (size_t)N_ROWS * sizeof(uint32);
    const size_t FLG_BYTES   = (size_t)N_ROWS * sizeof(uint32);
    const size_t WB_BYTES    = (size_t)D_IN * D_DICT * sizeof(unsigned short);   // 8 MiB
    const size_t WEB_BYTES   = (size_t)D_DICT * D_IN * sizeof(unsigned short);   // 8 MiB
    const size_t XB_BYTES    = (size_t)N_ROWS * D_IN * sizeof(unsigned short);   // 16 MiB
    const size_t PAIRS_BYTES = (size_t)N_ROWS * 256 * sizeof(uint32);            // 16 MiB
    const size_t CAND_BYTES  = (size_t)N_ROWS * CAND_CAP * sizeof(uint2);        // 128 MiB
    const size_t FIXED_B     = CNT_BYTES + FLG_BYTES + WB_BYTES + WEB_BYTES +
                               XB_BYTES + PAIRS_BYTES + CAND_BYTES;
    const size_t ROW_BYTES   = (size_t)D_DICT * sizeof(float);

    char* ws = (char*)d_ws;

    if (ws_size >= FIXED_B) {
        uint32*         CandCnt = (uint32*)ws;
        uint32*         flags   = (uint32*)(ws + CNT_BYTES);
        unsigned short* Wb      = (unsigned short*)(ws + CNT_BYTES + FLG_BYTES);
        unsigned short* Web     = (unsigned short*)(ws + CNT_BYTES + FLG_BYTES + WB_BYTES);
        unsigned short* Xb      = (unsigned short*)(ws + CNT_BYTES + FLG_BYTES + WB_BYTES + WEB_BYTES);
        uint32*         Pairs   = (uint32*)(ws + CNT_BYTES + FLG_BYTES + WB_BYTES + WEB_BYTES + XB_BYTES);
        uint2*          Cand    = (uint2*)(ws + CNT_BYTES + FLG_BYTES + WB_BYTES + WEB_BYTES + XB_BYTES + PAIRS_BYTES);

        hipMemsetAsync(CandCnt, 0, CNT_BYTES + FLG_BYTES, stream);
        cast_swz_kernel<<<(D_IN * D_DICT / 8) / 256, 256, 0, stream>>>(W_dec, Wb, 10);
        cast_swz_kernel<<<(D_DICT * D_IN / 8) / 256, 256, 0, stream>>>(W_enc, Web, 6);
        cast_swz_kernel<<<(N_ROWS * D_IN / 8) / 256, 256, 0, stream>>>(x, Xb, 6);

        encode_mfma_cand<<<dim3(D_DICT / 128, N_ROWS / 128), 256, 0, stream>>>(
            Xb, Web, b_enc, Cand, CandCnt);
        select_kernel<<<N_ROWS, 256, 0, stream>>>(Cand, CandCnt, x, W_enc, b_enc,
                                                  Pairs, flags);
        repair_kernel<<<N_ROWS, 256, 0, stream>>>(flags, x, W_enc, b_enc, Pairs);

        mfma_decode_pairs<<<(N_ROWS / 64) * 2, 512, 0, stream>>>(Pairs, Wb, b_dec, recon, hidden);
    } else {
        float* pre = (float*)ws;
        long long cl = (long long)(ws_size / ROW_BYTES);
        int chunk;
        if (cl >= 128) { chunk = (cl > 2048) ? 2048 : (int)cl; chunk &= ~127; }
        else chunk = (cl < 1) ? 1 : (int)cl;

        for (int r0 = 0; r0 < N_ROWS; r0 += chunk) {
            int nr = (N_ROWS - r0 < chunk) ? (N_ROWS - r0) : chunk;
            dim3 grid((nr + 127) / 128, D_DICT / 128);
            encode_gemm_kernel<<<grid, 256, 0, stream>>>(x, W_enc, b_enc, pre, r0, nr);
            topk_band_kernel<<<nr, 256, 0, stream>>>(pre, r0, x, W_enc, b_enc, hidden);
        }
        decode_direct_kernel<<<N_ROWS, 256, 0, stream>>>(hidden, W_dec, b_dec, recon);
    }
}

// Round 26
// 896.061 us; speedup vs baseline: 1.0265x; 1.0265x over previous
//
#include <hip/hip_runtime.h>

typedef unsigned int uint32;
typedef unsigned long long uint64;
typedef __attribute__((ext_vector_type(4))) float  f32x4;
typedef __attribute__((ext_vector_type(8))) short  bf16x8;
typedef __attribute__((ext_vector_type(4))) unsigned short us4;
typedef __attribute__((ext_vector_type(8))) unsigned short us8;

#define N_ROWS   16384
#define D_IN     512
#define D_DICT   8192
#define TOPK     256
#define BAND     1.5e-2f
#define BCAP     64
#define CCAP     2048
#define CAND_CAP 1024
#define TFIX     1.38f
#define BINW     0.01f     // r19-r24-validated bin width

__device__ __forceinline__ unsigned short f2bf_rne(float f) {
    unsigned u = __float_as_uint(f);
    unsigned r = u + 0x7FFFu + ((u >> 16) & 1u);
    return (unsigned short)(r >> 16);
}
__device__ __forceinline__ float bf2f(unsigned short h) {
    return __uint_as_float(((unsigned)h) << 16);
}
__device__ __forceinline__ uint32 okey(float v) {
    uint32 u = __float_as_uint(v);
    return (u & 0x80000000u) ? ~u : (u | 0x80000000u);
}
__device__ __forceinline__ float inv_okey(uint32 u) {
    uint32 bits = (u & 0x80000000u) ? (u & 0x7FFFFFFFu) : ~u;
    return __uint_as_float(bits);
}
// XOR-swizzled LDS element address (validated r5-r24)
__device__ __forceinline__ int swz(int row, int k) {
    return row * 64 + (k ^ ((row & 7) << 3));
}
__device__ __forceinline__ void gll16(const unsigned short* g, unsigned short* l) {
    __builtin_amdgcn_global_load_lds(
        (const __attribute__((address_space(1))) unsigned int*)g,
        (__attribute__((address_space(3))) unsigned int*)l, 16, 0, 0);
}

// ---------------------------------------------------------------------------
// Kernel 0: fp32 -> bf16 cast with per-row LDS XOR swizzle baked in.
// ---------------------------------------------------------------------------
__launch_bounds__(256)
__global__ void cast_swz_kernel(const float* __restrict__ src,
                                unsigned short* __restrict__ dst,
                                int gprl) {
    int idx = blockIdx.x * 256 + threadIdx.x;
    int row = idx >> gprl;
    int g   = idx & ((1 << gprl) - 1);
    const float* s = src + ((size_t)idx << 3);
    us8 o;
    #pragma unroll
    for (int j = 0; j < 8; ++j) o[j] = f2bf_rne(s[j]);
    int gout = (g & ~7) | ((g ^ row) & 7);
    *(us8*)&dst[(((size_t)row << gprl) + gout) << 3] = o;
}

// ---------------------------------------------------------------------------
// Kernel 1 (v6): single-term bf16 MFMA encode + ballot candidate push
// (validated r22/r24: 3 blocks/CU, ballot epilogue).
// ---------------------------------------------------------------------------
__launch_bounds__(256, 3)
__global__ void encode_mfma_cand(const unsigned short* __restrict__ Xb,
                                 const unsigned short* __restrict__ Web,
                                 const float* __restrict__ b_enc,
                                 uint2* __restrict__ Cand,
                                 uint32* __restrict__ CandCnt) {
    __shared__ unsigned short At[128 * 64];
    __shared__ unsigned short Bt[128 * 64];

    int tid  = threadIdx.x;
    int lane = tid & 63;
    int wid  = tid >> 6;
    int wm   = wid >> 1;
    int wn   = wid & 1;
    int bn   = blockIdx.x * 128;
    int bm   = blockIdx.y * 128;
    int fr   = lane & 15;

    f32x4 acc[4][4];
    #pragma unroll
    for (int i = 0; i < 4; ++i)
        #pragma unroll
        for (int j = 0; j < 4; ++j) acc[i][j] = (f32x4)0.f;

    for (int c = 0; c < 8; ++c) {
        #pragma unroll
        for (int q = 0; q < 4; ++q) {
            int s = q * 256 + tid;
            int row = s >> 3;
            int g8  = (s & 7) * 8;
            gll16(&Xb[(size_t)(bm + row) * D_IN + c * 64 + g8], &At[row * 64 + g8]);
            gll16(&Web[(size_t)(bn + row) * D_IN + c * 64 + g8], &Bt[row * 64 + g8]);
        }
        __syncthreads();

        #pragma unroll
        for (int ks = 0; ks < 2; ++ks) {
            int kb = ks * 32 + (lane >> 4) * 8;
            bf16x8 av[4], bv[4];
            #pragma unroll
            for (int nj = 0; nj < 4; ++nj)
                bv[nj] = *(const bf16x8*)&Bt[swz(wn * 64 + nj * 16 + fr, kb)];
            #pragma unroll
            for (int mi = 0; mi < 4; ++mi)
                av[mi] = *(const bf16x8*)&At[swz(wm * 64 + mi * 16 + fr, kb)];
            #pragma unroll
            for (int mi = 0; mi < 4; ++mi)
                #pragma unroll
                for (int nj = 0; nj < 4; ++nj)
                    acc[mi][nj] = __builtin_amdgcn_mfma_f32_16x16x32_bf16(
                        av[mi], bv[nj], acc[mi][nj], 0, 0, 0);
        }
        __syncthreads();
    }

    float bcol[4];
    #pragma unroll
    for (int nj = 0; nj < 4; ++nj)
        bcol[nj] = b_enc[bn + wn * 64 + nj * 16 + fr];

    uint64 lowmask = (1ull << lane) - 1ull;
    uint64 grpmask = 0xFFFFull << (lane & 48);

    #pragma unroll
    for (int mi = 0; mi < 4; ++mi) {
        int rbase = bm + wm * 64 + mi * 16 + (lane >> 4) * 4;
        #pragma unroll
        for (int reg = 0; reg < 4; ++reg) {
            int r = rbase + reg;
            float v[4];
            uint64 m[4];
            #pragma unroll
            for (int nj = 0; nj < 4; ++nj) {
                v[nj] = acc[mi][nj][reg] + bcol[nj];
                m[nj] = __ballot(v[nj] > TFIX);
            }
            int c0 = __popcll(m[0] & grpmask);
            int c1 = __popcll(m[1] & grpmask);
            int c2 = __popcll(m[2] & grpmask);
            int c3 = __popcll(m[3] & grpmask);
            int total = c0 + c1 + c2 + c3;
            if (total > 0) {
                int base = 0;
                if (fr == 0) base = (int)atomicAdd(&CandCnt[r], (uint32)total);
                base = __shfl(base, lane & 48);
                int pre[4] = {0, c0, c0 + c1, c0 + c1 + c2};
                #pragma unroll
                for (int nj = 0; nj < 4; ++nj) {
                    if (v[nj] > TFIX) {
                        int slot = base + pre[nj] +
                                   __popcll(m[nj] & grpmask & lowmask);
                        if (slot < CAND_CAP)
                            Cand[(size_t)r * CAND_CAP + slot] =
                                make_uint2(__float_as_uint(v[nj]),
                                           (uint32)(bn + wn * 64 + nj * 16 + fr));
                    }
                }
            }
        }
    }
}

// ---------------------------------------------------------------------------
// Kernel 2: select — pairs only (validated r19-r24).
// ---------------------------------------------------------------------------
__launch_bounds__(256)
__global__ void select_kernel(const uint2* __restrict__ Cand,
                              const uint32* __restrict__ CandCnt,
                              const float* __restrict__ x,
                              const float* __restrict__ Wenc,
                              const float* __restrict__ b_enc,
                              uint32* __restrict__ Pairs,   // [N_ROWS][256]
                              uint32* __restrict__ flags) {
    __shared__ float  cand_val[CAND_CAP];
    __shared__ int    cand_idx[CAND_CAP];
    __shared__ uint32 hist[256];
    __shared__ uint32 pk[256];
    __shared__ uint64 bkey[BCAP];
    __shared__ int    sh_bin;
    __shared__ int    c_clear, bcnt;
    __shared__ int    bidx_s[BCAP];
    __shared__ float  bval_s[BCAP];

    int row = blockIdx.x;
    int t = threadIdx.x;

    int n = (int)CandCnt[row];
    bool ok = (n >= TOPK && n <= CAND_CAP);

    hist[t] = 0;
    if (t == 0) { sh_bin = 255; c_clear = 0; bcnt = 0; }
    if (ok) {
        for (int e = t; e < n; e += 256) {
            uint2 cv = Cand[(size_t)row * CAND_CAP + e];
            cand_val[e] = __uint_as_float(cv.x);
            cand_idx[e] = (int)cv.y;
        }
    }
    __syncthreads();

    float vL = 0.f, vU = 0.f;
    if (ok) {
        for (int e = t; e < n; e += 256) {
            int b = (int)((cand_val[e] - TFIX) * (1.f / BINW));
            b = b < 0 ? 0 : (b > 255 ? 255 : b);
            atomicAdd(&hist[b], 1u);
        }
        __syncthreads();
        if (t < 64) {
            uint4 h4 = *(const uint4*)&hist[t * 4];
            uint32 lsum = h4.x + h4.y + h4.z + h4.w;
            uint32 s = lsum;
            #pragma unroll
            for (int off = 1; off < 64; off <<= 1) {
                uint32 vv = __shfl_down(s, off);
                if (t + off < 64) s += vv;
            }
            uint32 above = s - lsum;
            uint32 suf3 = above + h4.w;
            uint32 suf2 = suf3 + h4.z;
            uint32 suf1 = suf2 + h4.y;
            uint32 suf0 = suf1 + h4.x;
            uint32 need = TOPK;
            if (above < need && suf0 >= need) {
                int j;
                if (suf3 >= need)      j = 3;
                else if (suf2 >= need) j = 2;
                else if (suf1 >= need) j = 1;
                else                   j = 0;
                sh_bin = t * 4 + j;
            }
        }
        __syncthreads();
        int b = sh_bin;
        vL = TFIX + BINW * b - 1e-3f;
        vU = TFIX + BINW * (b + 1) + 1e-3f;
        if (b >= 255) ok = false;
        if (!(vL - BAND - 1e-3f > TFIX)) ok = false;
    }

    if (!ok) {
        if (t == 0) flags[row] = 1u;
        return;
    }

    for (int e = t; e < n; e += 256) {
        float v = cand_val[e];
        int i = cand_idx[e];
        if (v > vU + BAND) {
            atomicAdd((uint32*)&c_clear, 1u);
        } else if (v >= vL - BAND) {
            int slot = atomicAdd((uint32*)&bcnt, 1u);
            if (slot < BCAP) bidx_s[slot] = i;
        }
    }
    __syncthreads();

    if (bcnt > BCAP) {
        if (t == 0) flags[row] = 1u;
        return;
    }

    if (t == 0) c_clear = 0;
    __syncthreads();
    for (int e = t; e < n; e += 256) {
        float v = cand_val[e];
        int i = cand_idx[e];
        if (v > vU + BAND) {
            int slot = atomicAdd((uint32*)&c_clear, 1u);
            pk[slot] = ((uint32)f2bf_rne(v) << 16) | (uint32)i;
        }
    }

    int nb = bcnt;
    if (t < nb) {
        const float* xr = x + (size_t)row * D_IN;
        const float* wr = Wenc + (size_t)bidx_s[t] * D_IN;
        float acc = 0.f;
        #pragma unroll 8
        for (int k = 0; k < D_IN; ++k)   // ascending k — np rounding class
            acc = fmaf(xr[k], wr[k], acc);
        bval_s[t] = acc + b_enc[bidx_s[t]];
    }
    if (t < BCAP)
        bkey[t] = 0xFFFFFFFFFFFFFFFFull;
    __syncthreads();
    if (t < nb)
        bkey[t] = ((uint64)(~okey(bval_s[t])) << 32) | (uint32)bidx_s[t];
    __syncthreads();
    for (int k = 2; k <= BCAP; k <<= 1) {
        for (int j = k >> 1; j > 0; j >>= 1) {
            if (t < BCAP) {
                int l = t ^ j;
                if (l > t) {
                    uint64 a = bkey[t], b = bkey[l];
                    bool up = ((t & k) == 0);
                    if ((a > b) == up) { bkey[t] = b; bkey[l] = a; }
                }
            }
            __syncthreads();
        }
    }
    int take = TOPK - c_clear;
    if (t < take) {
        uint64 key = bkey[t];
        uint32 ok32 = ~(uint32)(key >> 32);
        int    idx  = (int)(uint32)(key & 0xFFFFFFFFull);
        float  hv   = fmaxf(inv_okey(ok32), 0.f);
        pk[c_clear + t] = ((uint32)f2bf_rne(hv) << 16) | (uint32)idx;
    }
    __syncthreads();

    for (int k = 2; k <= 256; k <<= 1) {
        for (int j = k >> 1; j > 0; j >>= 1) {
            int l = t ^ j;
            if (l > t) {
                uint32 a = pk[t], b = pk[l];
                bool up = ((t & k) == 0);
                if (((a & 0xFFFFu) > (b & 0xFFFFu)) == up) { pk[t] = b; pk[l] = a; }
            }
            __syncthreads();
        }
    }
    Pairs[(size_t)row * 256 + t] = pk[t];
}

// ---------------------------------------------------------------------------
// Kernel 2b: exact repair for flagged rows — emits sorted Pairs (validated r18-r24).
// ---------------------------------------------------------------------------
__launch_bounds__(256)
__global__ void repair_kernel(const uint32* __restrict__ flags,
                              const float* __restrict__ x,
                              const float* __restrict__ Wenc,
                              const float* __restrict__ b_enc,
                              uint32* __restrict__ Pairs) {
    int row = blockIdx.x;
    if (flags[row] == 0u) return;
    __shared__ float  vals[D_DICT];
    __shared__ float  xs[D_IN];
    __shared__ uint32 hist[256];
    __shared__ uint32 pscan[257];
    __shared__ uint32 cnt_eq[256];
    __shared__ int    offs[257];
    __shared__ uint32 sh_prefix, sh_need;
    int t = threadIdx.x;

    for (int c = t; c < D_IN; c += 256) xs[c] = x[(size_t)row * D_IN + c];
    __syncthreads();
    for (int e = t; e < D_DICT; e += 256) {
        const float* wr = Wenc + (size_t)e * D_IN;
        float acc = 0.f;
        #pragma unroll 8
        for (int k = 0; k < D_IN; ++k)   // ascending k — np rounding class
            acc = fmaf(xs[k], wr[k], acc);
        vals[e] = acc + b_enc[e];
    }
    __syncthreads();

    uint32 prefix = 0, need = TOPK;
    for (int pass = 0; pass < 4; ++pass) {
        int shift = 24 - 8 * pass;
        hist[t] = 0;
        __syncthreads();
        uint32 mask_hi = pass ? (0xFFFFFFFFu << (shift + 8)) : 0u;
        #pragma unroll 4
        for (int c = 0; c < 32; ++c) {
            uint32 u = okey(vals[c * 256 + t]);
            if ((u & mask_hi) == prefix)
                atomicAdd(&hist[(u >> shift) & 255u], 1u);
        }
        __syncthreads();
        if (t == 0) {
            uint32 cum = 0;
            int d = 255;
            for (; d > 0; --d) {
                uint32 h = hist[d];
                if (cum + h >= need) break;
                cum += h;
            }
            sh_prefix = prefix | ((uint32)d << shift);
            sh_need = need - cum;
        }
        __syncthreads();
        prefix = sh_prefix;
        need = sh_need;
        __syncthreads();
    }
    uint32 T = prefix;
    uint32 r = need;

    #pragma unroll 2
    for (int c = 0; c < 32; ++c) {
        int i = c * 256 + t;
        uint32 u = okey(vals[i]);
        vals[i] = (u > T) ? fmaxf(vals[i], 0.f) : 0.f;
    }
    __syncthreads();

    cnt_eq[t] = 0;
    __syncthreads();
    {
        const float* xr = xs;
        for (int e = t; e < D_DICT; e += 256) {
            const float* wr = Wenc + (size_t)e * D_IN;
            float acc = 0.f;
            #pragma unroll 8
            for (int k = 0; k < D_IN; ++k)
                acc = fmaf(xr[k], wr[k], acc);
            float ov = acc + b_enc[e];
            if (okey(ov) == T) atomicAdd(&cnt_eq[e >> 5], 1u);
        }
    }
    __syncthreads();
    if (t == 0) {
        uint32 s = 0;
        for (int i = 0; i < 256; ++i) { pscan[i] = s; s += cnt_eq[i]; }
    }
    __syncthreads();
    {
        uint32 segbase = pscan[t];
        const float* xr = xs;
        uint32 rank = segbase;
        for (int j = 0; j < 32 && rank < r; ++j) {
            int i = t * 32 + j;
            const float* wr = Wenc + (size_t)i * D_IN;
            float acc = 0.f;
            #pragma unroll 8
            for (int k = 0; k < D_IN; ++k)
                acc = fmaf(xr[k], wr[k], acc);
            float ov = acc + b_enc[i];
            if (okey(ov) == T) {
                vals[i] = fmaxf(ov, 0.f);
                rank++;
            }
        }
    }
    __syncthreads();

    int base2 = t * 32;
    int c2 = 0;
    for (int j = 0; j < 32; ++j) c2 += (vals[base2 + j] > 0.f) ? 1 : 0;
    offs[t + 1] = c2;
    __syncthreads();
    if (t == 0) {
        offs[0] = 0;
        for (int i = 0; i < 256; ++i) offs[i + 1] += offs[i];
    }
    __syncthreads();
    int o = offs[t];
    for (int j = 0; j < 32; ++j) {
        float v = vals[base2 + j];
        if (v > 0.f) {
            Pairs[(size_t)row * 256 + o] =
                ((uint32)f2bf_rne(v) << 16) | (uint32)(base2 + j);
            ++o;
        }
    }
    __syncthreads();
    int total = offs[256];
    for (int e = total + t; e < 256; e += 256)
        Pairs[(size_t)row * 256 + e] = 0x0000FFFFu;
}

// ---------------------------------------------------------------------------
// Kernel 3 (v6): pairs decode, column-split 64x256 / 512 thr / grid 512
// (validated r21/r22/r24: best measured). Double-buffered At, 2 barriers/chunk,
// col-half-0 blocks write hidden.
// ---------------------------------------------------------------------------
__launch_bounds__(512)
__global__ void mfma_decode_pairs(const uint32* __restrict__ Pairs,
                                  const unsigned short* __restrict__ Wb,
                                  const float* __restrict__ b_dec,
                                  float* __restrict__ recon,
                                  float* __restrict__ hidden) {
    __shared__ unsigned short At[2][64 * 64];   // 16KB double-buffered
    __shared__ unsigned short Bt[256 * 64];     // 32KB
    __shared__ int curs[64];

    int tid  = threadIdx.x;
    int lane = tid & 63;
    int wn   = tid >> 6;
    int bid  = blockIdx.x;
    int ch   = bid & 1;
    int bm   = (bid >> 1) * 64;
    int fr   = lane & 15;
    int dbase = ch * 256;

    int pr_r = tid >> 3;
    int pr_j = tid & 7;
    int sub8 = (lane >> 3) * 8;
    const uint32* prow = Pairs + (size_t)(bm + pr_r) * 256;

    if (tid < 64) curs[tid] = 0;
    *(us8*)&At[0][tid * 8] = (us8)0;
    *(us8*)&At[1][tid * 8] = (us8)0;
    __syncthreads();

    f32x4 acc[4][2];
    #pragma unroll
    for (int i = 0; i < 4; ++i)
        #pragma unroll
        for (int j = 0; j < 2; ++j) acc[i][j] = (f32x4)0.f;

    for (int k0 = 0; k0 < D_DICT; k0 += 64) {
        int cur = (k0 >> 6) & 1;
        unsigned short* Ac = At[cur];

        #pragma unroll
        for (int q = 0; q < 4; ++q) {
            int s = q * 512 + tid;
            int row = s >> 3;
            int b8  = (s & 7) * 8;
            gll16(&Wb[(size_t)(dbase + row) * D_DICT + k0 + b8], &Bt[row * 64 + b8]);
        }
        {
            int kend = k0 + 64;
            int cur2 = curs[pr_r];
            for (;;) {
                int e = cur2 + pr_j;
                uint32 p = (e < 256) ? prow[e] : 0x0000FFFFu;
                int idx = (int)(p & 0xFFFFu);
                bool in = (idx < kend);
                if (in)
                    Ac[pr_r * 64 + ((idx - k0) ^ ((pr_r & 7) << 3))] =
                        (unsigned short)(p >> 16);
                uint64 mask = __ballot(in);
                int cnt = __popcll((mask >> sub8) & 0xFFull);
                cur2 += cnt;
                if (cnt < 8) break;
            }
            if (pr_j == 0) curs[pr_r] = cur2;
        }
        __syncthreads();

        if (ch == 0) {
            int row = tid >> 3;
            int g   = tid & 7;
            us8 w = *(const us8*)&Ac[row * 64 + g * 8];
            int lg = g ^ (row & 7);
            float* hdst = &hidden[(size_t)(bm + row) * D_DICT + k0 + lg * 8];
            float4 o0, o1;
            o0.x = bf2f(w[0]); o0.y = bf2f(w[1]);
            o0.z = bf2f(w[2]); o0.w = bf2f(w[3]);
            o1.x = bf2f(w[4]); o1.y = bf2f(w[5]);
            o1.z = bf2f(w[6]); o1.w = bf2f(w[7]);
            *(float4*)&hdst[0] = o0;
            *(float4*)&hdst[4] = o1;
        }

        #pragma unroll
        for (int ks = 0; ks < 2; ++ks) {
            int kb = ks * 32 + (lane >> 4) * 8;
            bf16x8 av[4], bv[2];
            #pragma unroll
            for (int mi = 0; mi < 4; ++mi)
                av[mi] = *(const bf16x8*)&Ac[swz(mi * 16 + fr, kb)];
            #pragma unroll
            for (int nj = 0; nj < 2; ++nj)
                bv[nj] = *(const bf16x8*)&Bt[swz(wn * 32 + nj * 16 + fr, kb)];
            #pragma unroll
            for (int mi = 0; mi < 4; ++mi)
                #pragma unroll
                for (int nj = 0; nj < 2; ++nj)
                    acc[mi][nj] = __builtin_amdgcn_mfma_f32_16x16x32_bf16(
                        av[mi], bv[nj], acc[mi][nj], 0, 0, 0);
        }

        *(us8*)&At[cur ^ 1][tid * 8] = (us8)0;
        __syncthreads();
    }

    #pragma unroll
    for (int mi = 0; mi < 4; ++mi) {
        int r0 = bm + mi * 16 + (lane >> 4) * 4;
        #pragma unroll
        for (int nj = 0; nj < 2; ++nj) {
            int col = dbase + wn * 32 + nj * 16 + fr;
            float bd = b_dec[col];
            #pragma unroll
            for (int reg = 0; reg < 4; ++reg)
                recon[(size_t)(r0 + reg) * D_IN + col] = acc[mi][nj][reg] + bd;
        }
    }
}

// ---------------------------------------------------------------------------
// Tier C fallback kernels (validated r10-r24)
// ---------------------------------------------------------------------------
#define EBK 8
#define ESTR 132

__launch_bounds__(256)
__global__ void encode_gemm_kernel(const float* __restrict__ X,
                                   const float* __restrict__ Wenc,
                                   const float* __restrict__ b_enc,
                                   float* __restrict__ P,
                                   int row0, int nrows) {
    __shared__ float As[EBK][ESTR];
    __shared__ float Bs[EBK][ESTR];
    int tid = threadIdx.x;
    int tx = tid & 15;
    int ty = tid >> 4;
    int bm = blockIdx.x * 128;
    int bn = blockIdx.y * 128;
    int srow = tid >> 1;
    int skq  = (tid & 1) * 4;

    float acc[8][8];
    #pragma unroll
    for (int i = 0; i < 8; ++i)
        #pragma unroll
        for (int j = 0; j < 8; ++j) acc[i][j] = 0.f;

    for (int k0 = 0; k0 < D_IN; k0 += EBK) {
        float4 a4 = make_float4(0.f, 0.f, 0.f, 0.f);
        if (bm + srow < nrows)
            a4 = *(const float4*)&X[(size_t)(row0 + bm + srow) * D_IN + k0 + skq];
        float4 b4 = *(const float4*)&Wenc[(size_t)(bn + srow) * D_IN + k0 + skq];
        As[skq + 0][srow] = a4.x; As[skq + 1][srow] = a4.y;
        As[skq + 2][srow] = a4.z; As[skq + 3][srow] = a4.w;
        Bs[skq + 0][srow] = b4.x; Bs[skq + 1][srow] = b4.y;
        Bs[skq + 2][srow] = b4.z; Bs[skq + 3][srow] = b4.w;
        __syncthreads();
        #pragma unroll
        for (int k = 0; k < EBK; ++k) {
            float4 a0 = *(const float4*)&As[k][ty * 4];
            float4 a1 = *(const float4*)&As[k][64 + ty * 4];
            float4 b0 = *(const float4*)&Bs[k][tx * 4];
            float4 b1 = *(const float4*)&Bs[k][64 + tx * 4];
            float a[8] = {a0.x, a0.y, a0.z, a0.w, a1.x, a1.y, a1.z, a1.w};
            float b[8] = {b0.x, b0.y, b0.z, b0.w, b1.x, b1.y, b1.z, b1.w};
            #pragma unroll
            for (int i = 0; i < 8; ++i)
                #pragma unroll
                for (int j = 0; j < 8; ++j)
                    acc[i][j] = fmaf(a[i], b[j], acc[i][j]);
        }
        __syncthreads();
    }

    float4 bias0 = *(const float4*)&b_enc[bn + tx * 4];
    float4 bias1 = *(const float4*)&b_enc[bn + 64 + tx * 4];
    float bb[8] = {bias0.x, bias0.y, bias0.z, bias0.w,
                   bias1.x, bias1.y, bias1.z, bias1.w};
    #pragma unroll
    for (int i = 0; i < 8; ++i) {
        int r = bm + (i < 4 ? ty * 4 + i : 64 + ty * 4 + (i - 4));
        if (r < nrows) {
            float4 o0, o1;
            o0.x = acc[i][0] + bb[0]; o0.y = acc[i][1] + bb[1];
            o0.z = acc[i][2] + bb[2]; o0.w = acc[i][3] + bb[3];
            o1.x = acc[i][4] + bb[4]; o1.y = acc[i][5] + bb[5];
            o1.z = acc[i][6] + bb[6]; o1.w = acc[i][7] + bb[7];
            *(float4*)&P[(size_t)r * D_DICT + bn + tx * 4] = o0;
            *(float4*)&P[(size_t)r * D_DICT + bn + 64 + tx * 4] = o1;
        }
    }
}

__launch_bounds__(256)
__global__ void topk_band_kernel(const float* __restrict__ P,
                                 int row0,
                                 const float* __restrict__ x,
                                 const float* __restrict__ Wenc,
                                 const float* __restrict__ b_enc,
                                 float* __restrict__ hidden) {
    __shared__ float  cand_val[CCAP];
    __shared__ int    cand_idx[CCAP];
    __shared__ uint32 hist[256];
    __shared__ float  redS[4], redS2[4];
    __shared__ float  sh_mu, sh_sig;
    __shared__ uint32 sh_prefix, sh_need;
    __shared__ int    sh_cnt, c_clear, bcnt;
    __shared__ int    bidx_s[BCAP];
    __shared__ float  bval_s[BCAP];

    int lrow = blockIdx.x;
    int grow = row0 + lrow;
    const float* p = P + (size_t)lrow * D_DICT;
    float* hrow = hidden + (size_t)grow * D_DICT;
    int t = threadIdx.x;

    if (t == 0) sh_cnt = 0;
    float s = 0.f, s2 = 0.f;
    #pragma unroll 2
    for (int c = 0; c < 8; ++c) {
        int e4 = c * 256 + t;
        float4 v4 = ((const float4*)p)[e4];
        s  += v4.x + v4.y + v4.z + v4.w;
        s2 += v4.x*v4.x + v4.y*v4.y + v4.z*v4.z + v4.w*v4.w;
        *(float4*)&hrow[e4 * 4] = make_float4(0.f, 0.f, 0.f, 0.f);
    }
    #pragma unroll
    for (int off = 32; off; off >>= 1) {
        s  += __shfl_down(s, off);
        s2 += __shfl_down(s2, off);
    }
    if ((t & 63) == 0) { redS[t >> 6] = s; redS2[t >> 6] = s2; }
    __syncthreads();
    if (t == 0) {
        float S  = redS[0] + redS[1] + redS[2] + redS[3];
        float S2 = redS2[0] + redS2[1] + redS2[2] + redS2[3];
        float mu = S * (1.f / D_DICT);
        float var = S2 * (1.f / D_DICT) - mu * mu;
        sh_mu = mu;
        sh_sig = sqrtf(fmaxf(var, 1e-20f));
    }
    __syncthreads();
    float Tlo = sh_mu + 1.3f * sh_sig;

    #pragma unroll 2
    for (int c = 0; c < 8; ++c) {
        int e4 = c * 256 + t;
        float4 v4 = ((const float4*)p)[e4];
        float vv[4] = {v4.x, v4.y, v4.z, v4.w};
        #pragma unroll
        for (int j = 0; j < 4; ++j) {
            if (vv[j] > Tlo) {
                int slot = atomicAdd((uint32*)&sh_cnt, 1u);
                if (slot < CCAP) { cand_val[slot] = vv[j]; cand_idx[slot] = e4 * 4 + j; }
            }
        }
    }
    __syncthreads();
    int n = sh_cnt;
    bool found = (n >= TOPK && n <= CCAP);

    float vT0 = 0.f;
    for (int rtry = 0; rtry < 2; ++rtry) {
        uint32 prefix = 0, need = TOPK;
        for (int pass = 0; pass < 4; ++pass) {
            int shift = 24 - 8 * pass;
            hist[t] = 0;
            __syncthreads();
            uint32 mask_hi = pass ? (0xFFFFFFFFu << (shift + 8)) : 0u;
            if (found) {
                for (int e = t; e < n; e += 256) {
                    uint32 u = okey(cand_val[e]);
                    if ((u & mask_hi) == prefix)
                        atomicAdd(&hist[(u >> shift) & 255u], 1u);
                }
            } else {
                for (int e = t; e < D_DICT; e += 256) {
                    uint32 u = okey(p[e]);
                    if ((u & mask_hi) == prefix)
                        atomicAdd(&hist[(u >> shift) & 255u], 1u);
                }
            }
            __syncthreads();
            if (t == 0) {
                uint32 cum = 0;
                int d = 255;
                for (; d > 0; --d) {
                    uint32 h = hist[d];
                    if (cum + h >= need) break;
                    cum += h;
                }
                sh_prefix = prefix | ((uint32)d << shift);
                sh_need = need - cum;
            }
            __syncthreads();
            prefix = sh_prefix;
            need = sh_need;
            __syncthreads();
        }
        uint32 tb = (prefix & 0x80000000u) ? (prefix & 0x7FFFFFFFu) : ~prefix;
        vT0 = __uint_as_float(tb);
        if (!found) break;
        if (vT0 - BAND - 1e-3f > Tlo) break;
        found = false;
        __syncthreads();
    }

    if (t == 0) { c_clear = 0; bcnt = 0; }
    __syncthreads();
    if (found) {
        for (int e = t; e < n; e += 256) {
            float v = cand_val[e];
            int i = cand_idx[e];
            if (v > vT0 + BAND) {
                hrow[i] = fmaxf(v, 0.f);
                atomicAdd((uint32*)&c_clear, 1u);
            } else if (v >= vT0 - BAND) {
                int slot = atomicAdd((uint32*)&bcnt, 1u);
                if (slot < BCAP) bidx_s[slot] = i;
            }
        }
    } else {
        for (int e = t; e < D_DICT; e += 256) {
            float v = p[e];
            if (v > vT0 + BAND) {
                hrow[e] = fmaxf(v, 0.f);
                atomicAdd((uint32*)&c_clear, 1u);
            } else if (v >= vT0 - BAND) {
                int slot = atomicAdd((uint32*)&bcnt, 1u);
                if (slot < BCAP) bidx_s[slot] = e;
            }
        }
    }
    __syncthreads();

    int nb = bcnt < BCAP ? bcnt : BCAP;
    if (t < nb) {
        const float* xr = x + (size_t)grow * D_IN;
        const float* wr = Wenc + (size_t)bidx_s[t] * D_IN;
        float acc = 0.f;
        #pragma unroll 8
        for (int k = 0; k < D_IN; ++k)
            acc = fmaf(xr[k], wr[k], acc);
        bval_s[t] = acc + b_enc[bidx_s[t]];
    }
    __syncthreads();
    if (t == 0) {
        int take = TOPK - c_clear;
        for (int rr = 0; rr < take; ++rr) {
            int best = -1; float bv = 0.f; int bi = 0;
            for (int e = 0; e < nb; ++e) {
                int idx = bidx_s[e];
                if (idx < 0) continue;
                float v = bval_s[e];
                if (best < 0 || v > bv || (v == bv && idx < bi)) {
                    best = e; bv = v; bi = idx;
                }
            }
            if (best < 0) break;
            bidx_s[best] = -1;
            hrow[bi] = fmaxf(bv, 0.f);
        }
    }
}

__launch_bounds__(256)
__global__ void decode_direct_kernel(const float* __restrict__ hidden,
                                     const float* __restrict__ W_dec,
                                     const float* __restrict__ b_dec,
                                     float* __restrict__ recon) {
    __shared__ float  sv[TOPK];
    __shared__ int    sidx[TOPK];
    __shared__ int    offs[257];
    int row = blockIdx.x;
    int t = threadIdx.x;
    const float* hrow = hidden + (size_t)row * D_DICT;

    int base = t * 32;
    int c = 0;
    for (int j = 0; j < 32; ++j) c += (hrow[base + j] > 0.f) ? 1 : 0;
    offs[t + 1] = c;
    __syncthreads();
    if (t == 0) {
        offs[0] = 0;
        for (int i = 0; i < 256; ++i) offs[i + 1] += offs[i];
    }
    __syncthreads();
    int o = offs[t];
    for (int j = 0; j < 32; ++j) {
        float v = hrow[base + j];
        if (v > 0.f) { sv[o] = v; sidx[o] = base + j; ++o; }
    }
    __syncthreads();
    int total = offs[256];

    int d0 = 2 * t;
    float acc0 = b_dec[d0];
    float acc1 = b_dec[d0 + 1];
    for (int k = 0; k < total; ++k) {
        float v = sv[k];
        int idx = sidx[k];
        acc0 = fmaf(v, W_dec[(size_t)d0 * D_DICT + idx], acc0);
        acc1 = fmaf(v, W_dec[(size_t)(d0 + 1) * D_DICT + idx], acc1);
    }
    *(float2*)&recon[(size_t)row * D_IN + d0] = make_float2(acc0, acc1);
}

// ---------------------------------------------------------------------------
extern "C" void kernel_launch(void* const* d_in, const int* in_sizes, int n_in,
                              void* d_out, int out_size, void* d_ws, size_t ws_size,
                              hipStream_t stream) {
    const float* x     = (const float*)d_in[0];
    const float* W_enc = (const float*)d_in[1];
    const float* b_enc = (const float*)d_in[2];
    const float* W_dec = (const float*)d_in[3];
    const float* b_dec = (const float*)d_in[4];

    float* out    = (float*)d_out;
    float* recon  = out;                          // 16384*512 fp32
    float* hidden = out + (size_t)N_ROWS * D_IN;  // 16384*8192 fp32

    const size_t CNT_BYTES   = (size_t)N_ROWS * sizeof(uint32);
    const size_t FLG_BYTES   = (size_t)N_ROWS * sizeof(uint32);
    const size_t WB_BYTES    = (size_t)D_IN * D_DICT * sizeof(unsigned short);   // 8 MiB
    const size_t WEB_BYTES   = (size_t)D_DICT * D_IN * sizeof(unsigned short);   // 8 MiB
    const size_t XB_BYTES    = (size_t)N_ROWS * D_IN * sizeof(unsigned short);   // 16 MiB
    const size_t PAIRS_BYTES = (size_t)N_ROWS * 256 * sizeof(uint32);            // 16 MiB
    const size_t CAND_BYTES  = (size_t)N_ROWS * CAND_CAP * sizeof(uint2);        // 128 MiB
    const size_t FIXED_B     = CNT_BYTES + FLG_BYTES + WB_BYTES + WEB_BYTES +
                               XB_BYTES + PAIRS_BYTES + CAND_BYTES;
    const size_t ROW_BYTES   = (size_t)D_DICT * sizeof(float);

    char* ws = (char*)d_ws;

    if (ws_size >= FIXED_B) {
        uint32*         CandCnt = (uint32*)ws;
        uint32*         flags   = (uint32*)(ws + CNT_BYTES);
        unsigned short* Wb      = (unsigned short*)(ws + CNT_BYTES + FLG_BYTES);
        unsigned short* Web     = (unsigned short*)(ws + CNT_BYTES + FLG_BYTES + WB_BYTES);
        unsigned short* Xb      = (unsigned short*)(ws + CNT_BYTES + FLG_BYTES + WB_BYTES + WEB_BYTES);
        uint32*         Pairs   = (uint32*)(ws + CNT_BYTES + FLG_BYTES + WB_BYTES + WEB_BYTES + XB_BYTES);
        uint2*          Cand    = (uint2*)(ws + CNT_BYTES + FLG_BYTES + WB_BYTES + WEB_BYTES + XB_BYTES + PAIRS_BYTES);

        hipMemsetAsync(CandCnt, 0, CNT_BYTES + FLG_BYTES, stream);
        cast_swz_kernel<<<(D_IN * D_DICT / 8) / 256, 256, 0, stream>>>(W_dec, Wb, 10);
        cast_swz_kernel<<<(D_DICT * D_IN / 8) / 256, 256, 0, stream>>>(W_enc, Web, 6);
        cast_swz_kernel<<<(N_ROWS * D_IN / 8) / 256, 256, 0, stream>>>(x, Xb, 6);

        encode_mfma_cand<<<dim3(D_DICT / 128, N_ROWS / 128), 256, 0, stream>>>(
            Xb, Web, b_enc, Cand, CandCnt);
        select_kernel<<<N_ROWS, 256, 0, stream>>>(Cand, CandCnt, x, W_enc, b_enc,
                                                  Pairs, flags);
        repair_kernel<<<N_ROWS, 256, 0, stream>>>(flags, x, W_enc, b_enc, Pairs);

        mfma_decode_pairs<<<(N_ROWS / 64) * 2, 512, 0, stream>>>(Pairs, Wb, b_dec, recon, hidden);
    } else {
        float* pre = (float*)ws;
        long long cl = (long long)(ws_size / ROW_BYTES);
        int chunk;
        if (cl >= 128) { chunk = (cl > 2048) ? 2048 : (int)cl; chunk &= ~127; }
        else chunk = (cl < 1) ? 1 : (int)cl;

        for (int r0 = 0; r0 < N_ROWS; r0 += chunk) {
            int nr = (N_ROWS - r0 < chunk) ? (N_ROWS - r0) : chunk;
            dim3 grid((nr + 127) / 128, D_DICT / 128);
            encode_gemm_kernel<<<grid, 256, 0, stream>>>(x, W_enc, b_enc, pre, r0, nr);
            topk_band_kernel<<<nr, 256, 0, stream>>>(pre, r0, x, W_enc, b_enc, hidden);
        }
        decode_direct_kernel<<<N_ROWS, 256, 0, stream>>>(hidden, W_dec, b_dec, recon);
    }
}